// Round 1
// baseline (829.447 us; speedup 1.0000x reference)
//
#include <hip/hip_runtime.h>
#include <math.h>

// ---------------------------------------------------------------------------
// InteractionBlock: gather -> per-edge tensor-product -> scatter-add -> linear
// N=50000 nodes, E=800000 edges, MUL=32.
// ws layout (floats): s1[N*32] | v1[N*96] | S[N*64] | V[N*192]  (76.8 MB)
// v1 stored as [n][i][u] (i=xyz, u=channel) so 32-lane groups are contiguous.
// V  stored as [n][i][uu] (uu in [0,64)) for contiguous atomic groups.
// ---------------------------------------------------------------------------

#define MULC 32

__global__ __launch_bounds__(256) void node_prep(
    const float* __restrict__ nf, const float* __restrict__ W1_s,
    const float* __restrict__ W1_v, float* __restrict__ s1,
    float* __restrict__ v1, int N)
{
    int tid = blockIdx.x * 256 + threadIdx.x;
    int n = tid >> 5;
    int w = tid & 31;
    if (n >= N) return;
    const float l1 = 0.17677669529663687f; // 1/sqrt(32)
    const float* row = nf + (size_t)n * 128;
    float ss = 0.f, vx = 0.f, vy = 0.f, vz = 0.f;
#pragma unroll
    for (int u = 0; u < 32; ++u) {
        float ws = W1_s[u * 32 + w];
        float wv = W1_v[u * 32 + w];
        ss += row[u] * ws;
        vx += row[32 + u * 3 + 0] * wv;
        vy += row[32 + u * 3 + 1] * wv;
        vz += row[32 + u * 3 + 2] * wv;
    }
    s1[(size_t)n * 32 + w] = ss * l1;
    v1[(size_t)n * 96 + 0 * 32 + w] = vx * l1;
    v1[(size_t)n * 96 + 1 * 32 + w] = vy * l1;
    v1[(size_t)n * 96 + 2 * 32 + w] = vz * l1;
}

__global__ __launch_bounds__(256) void edge_kernel(
    const float* __restrict__ ea, const float* __restrict__ ee,
    const float* __restrict__ fc1, const float* __restrict__ fc2,
    const float* __restrict__ s1, const float* __restrict__ v1,
    const int* __restrict__ eidx, float* __restrict__ S, float* __restrict__ V,
    int E)
{
    long long tid = (long long)blockIdx.x * 256 + threadIdx.x;
    int e = (int)(tid >> 5);
    int u = (int)(tid & 31);
    if (e >= E) return;
    const float rs8 = 0.35355339059327373f;       // 1/sqrt(8)
    const float inv_sqrt3 = 0.5773502691896258f;

    // small MLP: h = silu(ee @ fc_w1 / sqrt(8)); w = h @ fc_w2 / sqrt(8)
    float eev[8];
#pragma unroll
    for (int i = 0; i < 8; ++i) eev[i] = ee[(size_t)e * 8 + i];
    float h[8];
#pragma unroll
    for (int k = 0; k < 8; ++k) {
        float t = 0.f;
#pragma unroll
        for (int i = 0; i < 8; ++i) t += eev[i] * fc1[i * 8 + k];
        t *= rs8;
        h[k] = t / (1.f + expf(-t));
    }
    float w0 = 0.f, w1 = 0.f, w2 = 0.f, w3 = 0.f;
#pragma unroll
    for (int k = 0; k < 8; ++k) {
        const float* f2 = fc2 + k * 128;
        float hk = h[k];
        w0 += hk * f2[u];
        w1 += hk * f2[32 + u];
        w2 += hk * f2[64 + u];
        w3 += hk * f2[96 + u];
    }
    w0 *= rs8; w1 *= rs8; w2 *= rs8; w3 *= rs8;

    int dst = eidx[e];       // edge_index[0]
    int src = eidx[E + e];   // edge_index[1]
    float a0 = ea[(size_t)e * 4 + 0];
    float ax = ea[(size_t)e * 4 + 1];
    float ay = ea[(size_t)e * 4 + 2];
    float az = ea[(size_t)e * 4 + 3];
    float ss = s1[(size_t)src * 32 + u];
    float vx = v1[(size_t)src * 96 + 0 * 32 + u];
    float vy = v1[(size_t)src * 96 + 1 * 32 + u];
    float vz = v1[(size_t)src * 96 + 2 * 32 + u];
    float dv = vx * ax + vy * ay + vz * az;

    float* Sr = S + (size_t)dst * 64;
    float* Vr = V + (size_t)dst * 192;
    atomicAdd(Sr + u,      w0 * ss * a0);
    atomicAdd(Sr + 32 + u, w3 * dv * inv_sqrt3);
    float c1 = w1 * ss;
    atomicAdd(Vr + 0 * 64 + u, c1 * ax);
    atomicAdd(Vr + 1 * 64 + u, c1 * ay);
    atomicAdd(Vr + 2 * 64 + u, c1 * az);
    float c2 = w2 * a0;
    atomicAdd(Vr + 0 * 64 + 32 + u, c2 * vx);
    atomicAdd(Vr + 1 * 64 + 32 + u, c2 * vy);
    atomicAdd(Vr + 2 * 64 + 32 + u, c2 * vz);
}

__global__ __launch_bounds__(256) void node_final(
    const float* __restrict__ S, const float* __restrict__ V,
    const float* __restrict__ W2_s, const float* __restrict__ W2_v,
    const float* __restrict__ nf, const float* __restrict__ nattr,
    const float* __restrict__ Wsc_s, const float* __restrict__ Wsc_v,
    float* __restrict__ out, int N)
{
    int tid = blockIdx.x * 256 + threadIdx.x;
    int n = tid >> 5;
    int w = tid & 31;
    if (n >= N) return;
    const float l2 = 0.125f;                    // 1/sqrt(64)
    const float sc_norm = 0.08838834764831843f; // 1/sqrt(128)
    const float* Sr = S + (size_t)n * 64;
    const float* Vr = V + (size_t)n * 192;
    float sa = 0.f, va0 = 0.f, va1 = 0.f, va2 = 0.f;
#pragma unroll 8
    for (int j = 0; j < 64; ++j) {
        float w2s = W2_s[j * 32 + w];
        float w2v = W2_v[j * 32 + w];
        sa  += Sr[j] * w2s;
        va0 += Vr[0 * 64 + j] * w2v;
        va1 += Vr[1 * 64 + j] * w2v;
        va2 += Vr[2 * 64 + j] * w2v;
    }
    sa *= l2; va0 *= l2; va1 *= l2; va2 *= l2;

    float at0 = nattr[(size_t)n * 4 + 0];
    float at1 = nattr[(size_t)n * 4 + 1];
    float at2 = nattr[(size_t)n * 4 + 2];
    float at3 = nattr[(size_t)n * 4 + 3];
    const float* row = nf + (size_t)n * 128;
    float scs = 0.f, scv0 = 0.f, scv1 = 0.f, scv2 = 0.f;
#pragma unroll 4
    for (int u = 0; u < 32; ++u) {
        const float* ps = Wsc_s + (size_t)(u * 4) * 32 + w;
        const float* pv = Wsc_v + (size_t)(u * 4) * 32 + w;
        float cs = at0 * ps[0] + at1 * ps[32] + at2 * ps[64] + at3 * ps[96];
        float cv = at0 * pv[0] + at1 * pv[32] + at2 * pv[64] + at3 * pv[96];
        scs  += row[u] * cs;
        scv0 += row[32 + u * 3 + 0] * cv;
        scv1 += row[32 + u * 3 + 1] * cv;
        scv2 += row[32 + u * 3 + 2] * cv;
    }
    float* orow = out + (size_t)n * 128;
    orow[w] = sa + scs * sc_norm;
    orow[32 + w * 3 + 0] = va0 + scv0 * sc_norm;
    orow[32 + w * 3 + 1] = va1 + scv1 * sc_norm;
    orow[32 + w * 3 + 2] = va2 + scv2 * sc_norm;
}

extern "C" void kernel_launch(void* const* d_in, const int* in_sizes, int n_in,
                              void* d_out, int out_size, void* d_ws, size_t ws_size,
                              hipStream_t stream) {
    const float* nf    = (const float*)d_in[0];
    const float* nattr = (const float*)d_in[1];
    const float* ea    = (const float*)d_in[2];
    const float* ee    = (const float*)d_in[3];
    const float* W1_s  = (const float*)d_in[4];
    const float* W1_v  = (const float*)d_in[5];
    const float* fc1   = (const float*)d_in[6];
    const float* fc2   = (const float*)d_in[7];
    const float* W2_s  = (const float*)d_in[8];
    const float* W2_v  = (const float*)d_in[9];
    const float* Wsc_s = (const float*)d_in[10];
    const float* Wsc_v = (const float*)d_in[11];
    const int*   eidx  = (const int*)d_in[12];

    int N = in_sizes[0] / 128;
    int E = in_sizes[12] / 2;

    float* ws = (float*)d_ws;
    float* s1 = ws;                           // N*32
    float* v1 = s1 + (size_t)N * 32;          // N*96
    float* S  = v1 + (size_t)N * 96;          // N*64
    float* V  = S  + (size_t)N * 64;          // N*192

    // zero the scatter accumulators (ws is poisoned, not re-poisoned between
    // replays -> must zero every launch for determinism)
    hipMemsetAsync(S, 0, (size_t)N * 256 * sizeof(float), stream);

    int nb_node = (N * 32 + 255) / 256;
    node_prep<<<nb_node, 256, 0, stream>>>(nf, W1_s, W1_v, s1, v1, N);

    long long tot = (long long)E * 32;
    int nb_edge = (int)((tot + 255) / 256);
    edge_kernel<<<nb_edge, 256, 0, stream>>>(ea, ee, fc1, fc2, s1, v1, eidx, S, V, E);

    node_final<<<nb_node, 256, 0, stream>>>(S, V, W2_s, W2_v, nf, nattr,
                                            Wsc_s, Wsc_v, (float*)d_out, N);
}

// Round 2
// 374.741 us; speedup vs baseline: 2.2134x; 2.2134x over previous
//
#include <hip/hip_runtime.h>
#include <math.h>

// ---------------------------------------------------------------------------
// InteractionBlock: gather -> per-edge tensor-product -> scatter -> linear
// N=50000 nodes, E=800000 edges, MUL=32.
//
// Round-2 strategy: counting-sort edges by dst, then per-node atomic-free
// reduction (32-lane group per node). Eliminates 204.8M f32 atomics
// (= 819 MB of memory-side writes, the round-1 bottleneck).
//
// ws layout (4B units):
//   s1[N*32] | v1[N*96] | S[N*64] | V[N*192] | cnt[N] | rs[N] |
//   bsum[64] | boff[64] | perm[E]                       (~80.4 MB)
// ---------------------------------------------------------------------------

__global__ __launch_bounds__(256) void node_prep(
    const float* __restrict__ nf, const float* __restrict__ W1_s,
    const float* __restrict__ W1_v, float* __restrict__ s1,
    float* __restrict__ v1, int N)
{
    int tid = blockIdx.x * 256 + threadIdx.x;
    int n = tid >> 5;
    int w = tid & 31;
    if (n >= N) return;
    const float l1 = 0.17677669529663687f; // 1/sqrt(32)
    const float* row = nf + (size_t)n * 128;
    float ss = 0.f, vx = 0.f, vy = 0.f, vz = 0.f;
#pragma unroll
    for (int u = 0; u < 32; ++u) {
        float ws = W1_s[u * 32 + w];
        float wv = W1_v[u * 32 + w];
        ss += row[u] * ws;
        vx += row[32 + u * 3 + 0] * wv;
        vy += row[32 + u * 3 + 1] * wv;
        vz += row[32 + u * 3 + 2] * wv;
    }
    s1[(size_t)n * 32 + w] = ss * l1;
    v1[(size_t)n * 96 + 0 * 32 + w] = vx * l1;
    v1[(size_t)n * 96 + 1 * 32 + w] = vy * l1;
    v1[(size_t)n * 96 + 2 * 32 + w] = vz * l1;
}

// ---------------- CSR build ----------------

__global__ __launch_bounds__(256) void hist_kernel(
    const int* __restrict__ eidx, int* __restrict__ cnt, int E)
{
    int e = blockIdx.x * 256 + threadIdx.x;
    if (e < E) atomicAdd(cnt + eidx[e], 1);
}

__global__ __launch_bounds__(1024) void scan_a(
    const int* __restrict__ cnt, int* __restrict__ rs,
    int* __restrict__ bsum, int N)
{
    int i = blockIdx.x * 1024 + threadIdx.x;
    int lane = threadIdx.x & 63;
    int wid = threadIdx.x >> 6;
    int v = (i < N) ? cnt[i] : 0;
    int incl = v;
#pragma unroll
    for (int d = 1; d < 64; d <<= 1) {
        int t = __shfl_up(incl, d);
        if (lane >= d) incl += t;
    }
    __shared__ int wtot[16];
    __shared__ int woff[16];
    if (lane == 63) wtot[wid] = incl;
    __syncthreads();
    if (wid == 0) {
        int t = (lane < 16) ? wtot[lane] : 0;
        int s = t;
#pragma unroll
        for (int d = 1; d < 16; d <<= 1) {
            int q = __shfl_up(s, d);
            if (lane >= d) s += q;
        }
        if (lane < 16) woff[lane] = s - t;
        if (lane == 15) bsum[blockIdx.x] = s;
    }
    __syncthreads();
    if (i < N) rs[i] = woff[wid] + incl - v;
}

__global__ __launch_bounds__(64) void scan_b(
    const int* __restrict__ bsum, int* __restrict__ boff, int nb)
{
    int lane = threadIdx.x;
    int carry = 0;
    for (int base = 0; base < nb; base += 64) {
        int i = base + lane;
        int v = (i < nb) ? bsum[i] : 0;
        int s = v;
#pragma unroll
        for (int d = 1; d < 64; d <<= 1) {
            int t = __shfl_up(s, d);
            if (lane >= d) s += t;
        }
        if (i < nb) boff[i] = carry + s - v;
        carry += __shfl(s, 63);
    }
}

__global__ __launch_bounds__(1024) void scan_c(
    int* __restrict__ rs, const int* __restrict__ boff, int N)
{
    int i = blockIdx.x * 1024 + threadIdx.x;
    if (i < N) rs[i] += boff[blockIdx.x];
}

__global__ __launch_bounds__(256) void scatter_kernel(
    const int* __restrict__ eidx, int* __restrict__ rs,
    int* __restrict__ perm, int E)
{
    int e = blockIdx.x * 256 + threadIdx.x;
    if (e < E) {
        int d = eidx[e];
        int p = atomicAdd(rs + d, 1);
        perm[p] = e;
    }
}

// ---------------- per-node reduction (no atomics) ----------------
// 32-lane group per node (8 groups / 256-thread block). Phase 1: lane l runs
// the edge MLP for edge slot l, stashes {h*rs8, a0..a3, src} in LDS (same-wave
// visibility, no barrier needed: groups never cross a wave boundary).
// Phase 2: lanes = channels u, broadcast-read LDS record, coalesced gather of
// s1/v1[src], accumulate in registers.

__global__ __launch_bounds__(256) void reduce_kernel(
    const float* __restrict__ ea, const float* __restrict__ ee,
    const float* __restrict__ fc1, const float* __restrict__ fc2,
    const float* __restrict__ s1, const float* __restrict__ v1,
    const int* __restrict__ eidx, const int* __restrict__ perm,
    const int* __restrict__ rs_end, const int* __restrict__ cnt,
    float* __restrict__ S, float* __restrict__ V, int N, int E)
{
    __shared__ float rec[8][32][16]; // 16 KB
    int g = threadIdx.x >> 5;
    int u = threadIdx.x & 31;
    int n = blockIdx.x * 8 + g;
    if (n >= N) return;

    const float rs8 = 0.35355339059327373f;      // 1/sqrt(8)
    const float inv_sqrt3 = 0.5773502691896258f;

    // hoist fc2 columns for this lane into registers
    float f2r[8][4];
#pragma unroll
    for (int k = 0; k < 8; ++k)
#pragma unroll
        for (int j = 0; j < 4; ++j)
            f2r[k][j] = fc2[k * 128 + j * 32 + u];

    int count = cnt[n];
    int end = rs_end[n];     // after scatter: rs[n] = start + cnt[n]
    int start = end - count;

    float aS0 = 0.f, aS1 = 0.f;
    float aV0x = 0.f, aV0y = 0.f, aV0z = 0.f;
    float aV1x = 0.f, aV1y = 0.f, aV1z = 0.f;

    for (int j0 = 0; j0 < count; j0 += 32) {
        int nk = count - j0; if (nk > 32) nk = 32;
        // phase 1
        if (u < nk) {
            int e = perm[start + j0 + u];
            float eev[8];
#pragma unroll
            for (int i = 0; i < 8; ++i) eev[i] = ee[(size_t)e * 8 + i];
            float* r = &rec[g][u][0];
#pragma unroll
            for (int k = 0; k < 8; ++k) {
                float t = 0.f;
#pragma unroll
                for (int i = 0; i < 8; ++i) t += eev[i] * fc1[i * 8 + k];
                t *= rs8;
                float sl = t / (1.f + expf(-t));
                r[k] = sl * rs8;               // fold the 1/sqrt(8) of w here
            }
            r[8]  = ea[(size_t)e * 4 + 0];
            r[9]  = ea[(size_t)e * 4 + 1];
            r[10] = ea[(size_t)e * 4 + 2];
            r[11] = ea[(size_t)e * 4 + 3];
            r[12] = __int_as_float(eidx[E + e]); // src
        }
        // phase 2 (same wave -> LDS writes above are visible, in-order)
        for (int jj = 0; jj < nk; ++jj) {
            const float* r = &rec[g][jj][0];
            float4 hA = *(const float4*)(r);
            float4 hB = *(const float4*)(r + 4);
            float4 aa = *(const float4*)(r + 8);
            int src = __float_as_int(r[12]);
            float ss = s1[src * 32 + u];
            const float* vp = v1 + src * 96;
            float vx = vp[u], vy = vp[32 + u], vz = vp[64 + u];

            float w0 = hA.x*f2r[0][0] + hA.y*f2r[1][0] + hA.z*f2r[2][0] + hA.w*f2r[3][0]
                     + hB.x*f2r[4][0] + hB.y*f2r[5][0] + hB.z*f2r[6][0] + hB.w*f2r[7][0];
            float w1 = hA.x*f2r[0][1] + hA.y*f2r[1][1] + hA.z*f2r[2][1] + hA.w*f2r[3][1]
                     + hB.x*f2r[4][1] + hB.y*f2r[5][1] + hB.z*f2r[6][1] + hB.w*f2r[7][1];
            float w2 = hA.x*f2r[0][2] + hA.y*f2r[1][2] + hA.z*f2r[2][2] + hA.w*f2r[3][2]
                     + hB.x*f2r[4][2] + hB.y*f2r[5][2] + hB.z*f2r[6][2] + hB.w*f2r[7][2];
            float w3 = hA.x*f2r[0][3] + hA.y*f2r[1][3] + hA.z*f2r[2][3] + hA.w*f2r[3][3]
                     + hB.x*f2r[4][3] + hB.y*f2r[5][3] + hB.z*f2r[6][3] + hB.w*f2r[7][3];

            float dv = vx * aa.y + vy * aa.z + vz * aa.w;
            aS0 += w0 * ss * aa.x;
            aS1 += w3 * dv;
            float c1 = w1 * ss;
            aV0x += c1 * aa.y; aV0y += c1 * aa.z; aV0z += c1 * aa.w;
            float c2 = w2 * aa.x;
            aV1x += c2 * vx; aV1y += c2 * vy; aV1z += c2 * vz;
        }
    }

    float* Sr = S + (size_t)n * 64;
    Sr[u] = aS0;
    Sr[32 + u] = aS1 * inv_sqrt3;
    float* Vr = V + (size_t)n * 192;
    Vr[0 * 64 + u] = aV0x;      Vr[0 * 64 + 32 + u] = aV1x;
    Vr[1 * 64 + u] = aV0y;      Vr[1 * 64 + 32 + u] = aV1y;
    Vr[2 * 64 + u] = aV0z;      Vr[2 * 64 + 32 + u] = aV1z;
}

// ---------------- fallback (round-1 atomic path) ----------------

__global__ __launch_bounds__(256) void edge_kernel(
    const float* __restrict__ ea, const float* __restrict__ ee,
    const float* __restrict__ fc1, const float* __restrict__ fc2,
    const float* __restrict__ s1, const float* __restrict__ v1,
    const int* __restrict__ eidx, float* __restrict__ S, float* __restrict__ V,
    int E)
{
    long long tid = (long long)blockIdx.x * 256 + threadIdx.x;
    int e = (int)(tid >> 5);
    int u = (int)(tid & 31);
    if (e >= E) return;
    const float rs8 = 0.35355339059327373f;
    const float inv_sqrt3 = 0.5773502691896258f;
    float eev[8];
#pragma unroll
    for (int i = 0; i < 8; ++i) eev[i] = ee[(size_t)e * 8 + i];
    float h[8];
#pragma unroll
    for (int k = 0; k < 8; ++k) {
        float t = 0.f;
#pragma unroll
        for (int i = 0; i < 8; ++i) t += eev[i] * fc1[i * 8 + k];
        t *= rs8;
        h[k] = t / (1.f + expf(-t));
    }
    float w0 = 0.f, w1 = 0.f, w2 = 0.f, w3 = 0.f;
#pragma unroll
    for (int k = 0; k < 8; ++k) {
        const float* f2 = fc2 + k * 128;
        float hk = h[k];
        w0 += hk * f2[u];
        w1 += hk * f2[32 + u];
        w2 += hk * f2[64 + u];
        w3 += hk * f2[96 + u];
    }
    w0 *= rs8; w1 *= rs8; w2 *= rs8; w3 *= rs8;
    int dst = eidx[e];
    int src = eidx[E + e];
    float a0 = ea[(size_t)e * 4 + 0];
    float ax = ea[(size_t)e * 4 + 1];
    float ay = ea[(size_t)e * 4 + 2];
    float az = ea[(size_t)e * 4 + 3];
    float ss = s1[(size_t)src * 32 + u];
    float vx = v1[(size_t)src * 96 + 0 * 32 + u];
    float vy = v1[(size_t)src * 96 + 1 * 32 + u];
    float vz = v1[(size_t)src * 96 + 2 * 32 + u];
    float dv = vx * ax + vy * ay + vz * az;
    float* Sr = S + (size_t)dst * 64;
    float* Vr = V + (size_t)dst * 192;
    atomicAdd(Sr + u,      w0 * ss * a0);
    atomicAdd(Sr + 32 + u, w3 * dv * inv_sqrt3);
    float c1 = w1 * ss;
    atomicAdd(Vr + 0 * 64 + u, c1 * ax);
    atomicAdd(Vr + 1 * 64 + u, c1 * ay);
    atomicAdd(Vr + 2 * 64 + u, c1 * az);
    float c2 = w2 * a0;
    atomicAdd(Vr + 0 * 64 + 32 + u, c2 * vx);
    atomicAdd(Vr + 1 * 64 + 32 + u, c2 * vy);
    atomicAdd(Vr + 2 * 64 + 32 + u, c2 * vz);
}

__global__ __launch_bounds__(256) void node_final(
    const float* __restrict__ S, const float* __restrict__ V,
    const float* __restrict__ W2_s, const float* __restrict__ W2_v,
    const float* __restrict__ nf, const float* __restrict__ nattr,
    const float* __restrict__ Wsc_s, const float* __restrict__ Wsc_v,
    float* __restrict__ out, int N)
{
    int tid = blockIdx.x * 256 + threadIdx.x;
    int n = tid >> 5;
    int w = tid & 31;
    if (n >= N) return;
    const float l2 = 0.125f;
    const float sc_norm = 0.08838834764831843f;
    const float* Sr = S + (size_t)n * 64;
    const float* Vr = V + (size_t)n * 192;
    float sa = 0.f, va0 = 0.f, va1 = 0.f, va2 = 0.f;
#pragma unroll 8
    for (int j = 0; j < 64; ++j) {
        float w2s = W2_s[j * 32 + w];
        float w2v = W2_v[j * 32 + w];
        sa  += Sr[j] * w2s;
        va0 += Vr[0 * 64 + j] * w2v;
        va1 += Vr[1 * 64 + j] * w2v;
        va2 += Vr[2 * 64 + j] * w2v;
    }
    sa *= l2; va0 *= l2; va1 *= l2; va2 *= l2;
    float at0 = nattr[(size_t)n * 4 + 0];
    float at1 = nattr[(size_t)n * 4 + 1];
    float at2 = nattr[(size_t)n * 4 + 2];
    float at3 = nattr[(size_t)n * 4 + 3];
    const float* row = nf + (size_t)n * 128;
    float scs = 0.f, scv0 = 0.f, scv1 = 0.f, scv2 = 0.f;
#pragma unroll 4
    for (int u = 0; u < 32; ++u) {
        const float* ps = Wsc_s + (size_t)(u * 4) * 32 + w;
        const float* pv = Wsc_v + (size_t)(u * 4) * 32 + w;
        float cs = at0 * ps[0] + at1 * ps[32] + at2 * ps[64] + at3 * ps[96];
        float cv = at0 * pv[0] + at1 * pv[32] + at2 * pv[64] + at3 * pv[96];
        scs  += row[u] * cs;
        scv0 += row[32 + u * 3 + 0] * cv;
        scv1 += row[32 + u * 3 + 1] * cv;
        scv2 += row[32 + u * 3 + 2] * cv;
    }
    float* orow = out + (size_t)n * 128;
    orow[w] = sa + scs * sc_norm;
    orow[32 + w * 3 + 0] = va0 + scv0 * sc_norm;
    orow[32 + w * 3 + 1] = va1 + scv1 * sc_norm;
    orow[32 + w * 3 + 2] = va2 + scv2 * sc_norm;
}

extern "C" void kernel_launch(void* const* d_in, const int* in_sizes, int n_in,
                              void* d_out, int out_size, void* d_ws, size_t ws_size,
                              hipStream_t stream) {
    const float* nf    = (const float*)d_in[0];
    const float* nattr = (const float*)d_in[1];
    const float* ea    = (const float*)d_in[2];
    const float* ee    = (const float*)d_in[3];
    const float* W1_s  = (const float*)d_in[4];
    const float* W1_v  = (const float*)d_in[5];
    const float* fc1   = (const float*)d_in[6];
    const float* fc2   = (const float*)d_in[7];
    const float* W2_s  = (const float*)d_in[8];
    const float* W2_v  = (const float*)d_in[9];
    const float* Wsc_s = (const float*)d_in[10];
    const float* Wsc_v = (const float*)d_in[11];
    const int*   eidx  = (const int*)d_in[12];

    int N = in_sizes[0] / 128;
    int E = in_sizes[12] / 2;

    float* ws = (float*)d_ws;
    float* s1 = ws;                           // N*32
    float* v1 = s1 + (size_t)N * 32;          // N*96
    float* S  = v1 + (size_t)N * 96;          // N*64
    float* V  = S  + (size_t)N * 64;          // N*192
    int* cnt  = (int*)(V + (size_t)N * 192);  // N
    int* rs   = cnt + N;                      // N
    int* bsum = rs + N;                       // 64
    int* boff = bsum + 64;                    // 64
    int* perm = boff + 64;                    // E

    size_t needed = ((size_t)N * 384 + 2 * (size_t)N + 128 + (size_t)E) * 4;

    int nb_node = (N * 32 + 255) / 256;
    int nbE = (E + 255) / 256;

    if (ws_size >= needed) {
        hipMemsetAsync(cnt, 0, (size_t)N * sizeof(int), stream);
        node_prep<<<nb_node, 256, 0, stream>>>(nf, W1_s, W1_v, s1, v1, N);
        hist_kernel<<<nbE, 256, 0, stream>>>(eidx, cnt, E);
        int nbS = (N + 1023) / 1024;
        scan_a<<<nbS, 1024, 0, stream>>>(cnt, rs, bsum, N);
        scan_b<<<1, 64, 0, stream>>>(bsum, boff, nbS);
        scan_c<<<nbS, 1024, 0, stream>>>(rs, boff, N);
        scatter_kernel<<<nbE, 256, 0, stream>>>(eidx, rs, perm, E);
        int nbR = (N + 7) / 8;
        reduce_kernel<<<nbR, 256, 0, stream>>>(ea, ee, fc1, fc2, s1, v1, eidx,
                                               perm, rs, cnt, S, V, N, E);
        node_final<<<nb_node, 256, 0, stream>>>(S, V, W2_s, W2_v, nf, nattr,
                                                Wsc_s, Wsc_v, (float*)d_out, N);
    } else {
        hipMemsetAsync(S, 0, (size_t)N * 256 * sizeof(float), stream);
        node_prep<<<nb_node, 256, 0, stream>>>(nf, W1_s, W1_v, s1, v1, N);
        long long tot = (long long)E * 32;
        int nb_edge = (int)((tot + 255) / 256);
        edge_kernel<<<nb_edge, 256, 0, stream>>>(ea, ee, fc1, fc2, s1, v1, eidx, S, V, E);
        node_final<<<nb_node, 256, 0, stream>>>(S, V, W2_s, W2_v, nf, nattr,
                                                Wsc_s, Wsc_v, (float*)d_out, N);
    }
}

// Round 3
// 304.207 us; speedup vs baseline: 2.7266x; 1.2319x over previous
//
#include <hip/hip_runtime.h>
#include <math.h>

// ---------------------------------------------------------------------------
// InteractionBlock: gather -> per-edge tensor-product -> scatter -> linear
// N=50000 nodes, E=800000 edges, MUL=32.
//
// Round-3: node_prep / node_final rewritten to eliminate broadcast global
// loads (768 VMEM instrs/wave -> ~45) by staging weights + per-node rows in
// LDS. Broadcasts now come from LDS (free). reduce/CSR unchanged.
//
// ws layout (4B units):
//   s1[N*32] | v1[N*96] | S[N*64] | V[N*192] | cnt[N] | rs[N] |
//   bsum[64] | boff[64] | perm[E]                       (~80.4 MB)
// ---------------------------------------------------------------------------

__global__ __launch_bounds__(256) void node_prep(
    const float* __restrict__ nf, const float* __restrict__ W1_s,
    const float* __restrict__ W1_v, float* __restrict__ s1,
    float* __restrict__ v1, int N)
{
    __shared__ float w1s[32 * 32];   // 4 KB
    __shared__ float w1v[32 * 32];   // 4 KB
    __shared__ float nrow[8][128];   // 4 KB

    int g = threadIdx.x >> 5;
    int w = threadIdx.x & 31;
    int n = blockIdx.x * 8 + g;

    // stage weights (whole block)
    for (int i = threadIdx.x; i < 1024; i += 256) {
        w1s[i] = W1_s[i];
        w1v[i] = W1_v[i];
    }
    // stage this group's node row (coalesced)
    if (n < N) {
        const float* row = nf + (size_t)n * 128;
        for (int k = w; k < 128; k += 32) nrow[g][k] = row[k];
    }
    __syncthreads();
    if (n >= N) return;

    const float l1 = 0.17677669529663687f; // 1/sqrt(32)
    const float* r = nrow[g];
    float ss = 0.f, vx = 0.f, vy = 0.f, vz = 0.f;
#pragma unroll 8
    for (int u = 0; u < 32; ++u) {
        float ws = w1s[u * 32 + w];
        float wv = w1v[u * 32 + w];
        ss += r[u] * ws;                    // LDS broadcast
        vx += r[32 + u * 3 + 0] * wv;
        vy += r[32 + u * 3 + 1] * wv;
        vz += r[32 + u * 3 + 2] * wv;
    }
    s1[(size_t)n * 32 + w] = ss * l1;
    v1[(size_t)n * 96 + 0 * 32 + w] = vx * l1;
    v1[(size_t)n * 96 + 1 * 32 + w] = vy * l1;
    v1[(size_t)n * 96 + 2 * 32 + w] = vz * l1;
}

// ---------------- CSR build ----------------

__global__ __launch_bounds__(256) void hist_kernel(
    const int* __restrict__ eidx, int* __restrict__ cnt, int E)
{
    int e = blockIdx.x * 256 + threadIdx.x;
    if (e < E) atomicAdd(cnt + eidx[e], 1);
}

__global__ __launch_bounds__(1024) void scan_a(
    const int* __restrict__ cnt, int* __restrict__ rs,
    int* __restrict__ bsum, int N)
{
    int i = blockIdx.x * 1024 + threadIdx.x;
    int lane = threadIdx.x & 63;
    int wid = threadIdx.x >> 6;
    int v = (i < N) ? cnt[i] : 0;
    int incl = v;
#pragma unroll
    for (int d = 1; d < 64; d <<= 1) {
        int t = __shfl_up(incl, d);
        if (lane >= d) incl += t;
    }
    __shared__ int wtot[16];
    __shared__ int woff[16];
    if (lane == 63) wtot[wid] = incl;
    __syncthreads();
    if (wid == 0) {
        int t = (lane < 16) ? wtot[lane] : 0;
        int s = t;
#pragma unroll
        for (int d = 1; d < 16; d <<= 1) {
            int q = __shfl_up(s, d);
            if (lane >= d) s += q;
        }
        if (lane < 16) woff[lane] = s - t;
        if (lane == 15) bsum[blockIdx.x] = s;
    }
    __syncthreads();
    if (i < N) rs[i] = woff[wid] + incl - v;
}

__global__ __launch_bounds__(64) void scan_b(
    const int* __restrict__ bsum, int* __restrict__ boff, int nb)
{
    int lane = threadIdx.x;
    int carry = 0;
    for (int base = 0; base < nb; base += 64) {
        int i = base + lane;
        int v = (i < nb) ? bsum[i] : 0;
        int s = v;
#pragma unroll
        for (int d = 1; d < 64; d <<= 1) {
            int t = __shfl_up(s, d);
            if (lane >= d) s += t;
        }
        if (i < nb) boff[i] = carry + s - v;
        carry += __shfl(s, 63);
    }
}

__global__ __launch_bounds__(1024) void scan_c(
    int* __restrict__ rs, const int* __restrict__ boff, int N)
{
    int i = blockIdx.x * 1024 + threadIdx.x;
    if (i < N) rs[i] += boff[blockIdx.x];
}

__global__ __launch_bounds__(256) void scatter_kernel(
    const int* __restrict__ eidx, int* __restrict__ rs,
    int* __restrict__ perm, int E)
{
    int e = blockIdx.x * 256 + threadIdx.x;
    if (e < E) {
        int d = eidx[e];
        int p = atomicAdd(rs + d, 1);
        perm[p] = e;
    }
}

// ---------------- per-node reduction (no atomics) ----------------

__global__ __launch_bounds__(256) void reduce_kernel(
    const float* __restrict__ ea, const float* __restrict__ ee,
    const float* __restrict__ fc1, const float* __restrict__ fc2,
    const float* __restrict__ s1, const float* __restrict__ v1,
    const int* __restrict__ eidx, const int* __restrict__ perm,
    const int* __restrict__ rs_end, const int* __restrict__ cnt,
    float* __restrict__ S, float* __restrict__ V, int N, int E)
{
    __shared__ float rec[8][32][16]; // 16 KB
    int g = threadIdx.x >> 5;
    int u = threadIdx.x & 31;
    int n = blockIdx.x * 8 + g;
    if (n >= N) return;

    const float rs8 = 0.35355339059327373f;      // 1/sqrt(8)
    const float inv_sqrt3 = 0.5773502691896258f;

    float f2r[8][4];
#pragma unroll
    for (int k = 0; k < 8; ++k)
#pragma unroll
        for (int j = 0; j < 4; ++j)
            f2r[k][j] = fc2[k * 128 + j * 32 + u];

    int count = cnt[n];
    int end = rs_end[n];     // after scatter: rs[n] = start + cnt[n]
    int start = end - count;

    float aS0 = 0.f, aS1 = 0.f;
    float aV0x = 0.f, aV0y = 0.f, aV0z = 0.f;
    float aV1x = 0.f, aV1y = 0.f, aV1z = 0.f;

    for (int j0 = 0; j0 < count; j0 += 32) {
        int nk = count - j0; if (nk > 32) nk = 32;
        if (u < nk) {
            int e = perm[start + j0 + u];
            float eev[8];
#pragma unroll
            for (int i = 0; i < 8; ++i) eev[i] = ee[(size_t)e * 8 + i];
            float* r = &rec[g][u][0];
#pragma unroll
            for (int k = 0; k < 8; ++k) {
                float t = 0.f;
#pragma unroll
                for (int i = 0; i < 8; ++i) t += eev[i] * fc1[i * 8 + k];
                t *= rs8;
                float sl = t / (1.f + expf(-t));
                r[k] = sl * rs8;
            }
            r[8]  = ea[(size_t)e * 4 + 0];
            r[9]  = ea[(size_t)e * 4 + 1];
            r[10] = ea[(size_t)e * 4 + 2];
            r[11] = ea[(size_t)e * 4 + 3];
            r[12] = __int_as_float(eidx[E + e]); // src
        }
        for (int jj = 0; jj < nk; ++jj) {
            const float* r = &rec[g][jj][0];
            float4 hA = *(const float4*)(r);
            float4 hB = *(const float4*)(r + 4);
            float4 aa = *(const float4*)(r + 8);
            int src = __float_as_int(r[12]);
            float ss = s1[src * 32 + u];
            const float* vp = v1 + src * 96;
            float vx = vp[u], vy = vp[32 + u], vz = vp[64 + u];

            float w0 = hA.x*f2r[0][0] + hA.y*f2r[1][0] + hA.z*f2r[2][0] + hA.w*f2r[3][0]
                     + hB.x*f2r[4][0] + hB.y*f2r[5][0] + hB.z*f2r[6][0] + hB.w*f2r[7][0];
            float w1 = hA.x*f2r[0][1] + hA.y*f2r[1][1] + hA.z*f2r[2][1] + hA.w*f2r[3][1]
                     + hB.x*f2r[4][1] + hB.y*f2r[5][1] + hB.z*f2r[6][1] + hB.w*f2r[7][1];
            float w2 = hA.x*f2r[0][2] + hA.y*f2r[1][2] + hA.z*f2r[2][2] + hA.w*f2r[3][2]
                     + hB.x*f2r[4][2] + hB.y*f2r[5][2] + hB.z*f2r[6][2] + hB.w*f2r[7][2];
            float w3 = hA.x*f2r[0][3] + hA.y*f2r[1][3] + hA.z*f2r[2][3] + hA.w*f2r[3][3]
                     + hB.x*f2r[4][3] + hB.y*f2r[5][3] + hB.z*f2r[6][3] + hB.w*f2r[7][3];

            float dv = vx * aa.y + vy * aa.z + vz * aa.w;
            aS0 += w0 * ss * aa.x;
            aS1 += w3 * dv;
            float c1 = w1 * ss;
            aV0x += c1 * aa.y; aV0y += c1 * aa.z; aV0z += c1 * aa.w;
            float c2 = w2 * aa.x;
            aV1x += c2 * vx; aV1y += c2 * vy; aV1z += c2 * vz;
        }
    }

    float* Sr = S + (size_t)n * 64;
    Sr[u] = aS0;
    Sr[32 + u] = aS1 * inv_sqrt3;
    float* Vr = V + (size_t)n * 192;
    Vr[0 * 64 + u] = aV0x;      Vr[0 * 64 + 32 + u] = aV1x;
    Vr[1 * 64 + u] = aV0y;      Vr[1 * 64 + 32 + u] = aV1y;
    Vr[2 * 64 + u] = aV0z;      Vr[2 * 64 + 32 + u] = aV1z;
}

// ---------------- fallback (round-1 atomic path) ----------------

__global__ __launch_bounds__(256) void edge_kernel(
    const float* __restrict__ ea, const float* __restrict__ ee,
    const float* __restrict__ fc1, const float* __restrict__ fc2,
    const float* __restrict__ s1, const float* __restrict__ v1,
    const int* __restrict__ eidx, float* __restrict__ S, float* __restrict__ V,
    int E)
{
    long long tid = (long long)blockIdx.x * 256 + threadIdx.x;
    int e = (int)(tid >> 5);
    int u = (int)(tid & 31);
    if (e >= E) return;
    const float rs8 = 0.35355339059327373f;
    const float inv_sqrt3 = 0.5773502691896258f;
    float eev[8];
#pragma unroll
    for (int i = 0; i < 8; ++i) eev[i] = ee[(size_t)e * 8 + i];
    float h[8];
#pragma unroll
    for (int k = 0; k < 8; ++k) {
        float t = 0.f;
#pragma unroll
        for (int i = 0; i < 8; ++i) t += eev[i] * fc1[i * 8 + k];
        t *= rs8;
        h[k] = t / (1.f + expf(-t));
    }
    float w0 = 0.f, w1 = 0.f, w2 = 0.f, w3 = 0.f;
#pragma unroll
    for (int k = 0; k < 8; ++k) {
        const float* f2 = fc2 + k * 128;
        float hk = h[k];
        w0 += hk * f2[u];
        w1 += hk * f2[32 + u];
        w2 += hk * f2[64 + u];
        w3 += hk * f2[96 + u];
    }
    w0 *= rs8; w1 *= rs8; w2 *= rs8; w3 *= rs8;
    int dst = eidx[e];
    int src = eidx[E + e];
    float a0 = ea[(size_t)e * 4 + 0];
    float ax = ea[(size_t)e * 4 + 1];
    float ay = ea[(size_t)e * 4 + 2];
    float az = ea[(size_t)e * 4 + 3];
    float ss = s1[(size_t)src * 32 + u];
    float vx = v1[(size_t)src * 96 + 0 * 32 + u];
    float vy = v1[(size_t)src * 96 + 1 * 32 + u];
    float vz = v1[(size_t)src * 96 + 2 * 32 + u];
    float dv = vx * ax + vy * ay + vz * az;
    float* Sr = S + (size_t)dst * 64;
    float* Vr = V + (size_t)dst * 192;
    atomicAdd(Sr + u,      w0 * ss * a0);
    atomicAdd(Sr + 32 + u, w3 * dv * inv_sqrt3);
    float c1 = w1 * ss;
    atomicAdd(Vr + 0 * 64 + u, c1 * ax);
    atomicAdd(Vr + 1 * 64 + u, c1 * ay);
    atomicAdd(Vr + 2 * 64 + u, c1 * az);
    float c2 = w2 * a0;
    atomicAdd(Vr + 0 * 64 + 32 + u, c2 * vx);
    atomicAdd(Vr + 1 * 64 + 32 + u, c2 * vy);
    atomicAdd(Vr + 2 * 64 + 32 + u, c2 * vz);
}

// ---------------- final linear + skip (LDS-staged, broadcast-free) --------

__global__ __launch_bounds__(256) void node_final(
    const float* __restrict__ S, const float* __restrict__ V,
    const float* __restrict__ W2_s, const float* __restrict__ W2_v,
    const float* __restrict__ nf, const float* __restrict__ nattr,
    const float* __restrict__ Wsc_s, const float* __restrict__ Wsc_v,
    float* __restrict__ out, int N)
{
    __shared__ float w2s[64 * 32];   // 8 KB
    __shared__ float w2v[64 * 32];   // 8 KB
    __shared__ float sv[8][256];     // 8 KB : S row (64) + V row (192)
    __shared__ float nrow[8][128];   // 4 KB

    int g = threadIdx.x >> 5;
    int w = threadIdx.x & 31;
    int n = blockIdx.x * 8 + g;

    for (int i = threadIdx.x; i < 2048; i += 256) {
        w2s[i] = W2_s[i];
        w2v[i] = W2_v[i];
    }
    if (n < N) {
        const float* Sr = S + (size_t)n * 64;
        const float* Vr = V + (size_t)n * 192;
        for (int k = w; k < 64; k += 32)  sv[g][k] = Sr[k];
        for (int k = w; k < 192; k += 32) sv[g][64 + k] = Vr[k];
        const float* row = nf + (size_t)n * 128;
        for (int k = w; k < 128; k += 32) nrow[g][k] = row[k];
    }
    __syncthreads();
    if (n >= N) return;

    const float l2 = 0.125f;                    // 1/sqrt(64)
    const float sc_norm = 0.08838834764831843f; // 1/sqrt(128)

    const float* svg = sv[g];
    float sa = 0.f, va0 = 0.f, va1 = 0.f, va2 = 0.f;
#pragma unroll 8
    for (int j = 0; j < 64; ++j) {
        float Sj = svg[j];                 // LDS broadcast (free)
        float w2sj = w2s[j * 32 + w];      // conflict-free
        float w2vj = w2v[j * 32 + w];
        sa  += Sj * w2sj;
        va0 += svg[64 + j]       * w2vj;
        va1 += svg[64 + 64 + j]  * w2vj;
        va2 += svg[64 + 128 + j] * w2vj;
    }
    sa *= l2; va0 *= l2; va1 *= l2; va2 *= l2;

    float at0 = nattr[(size_t)n * 4 + 0];
    float at1 = nattr[(size_t)n * 4 + 1];
    float at2 = nattr[(size_t)n * 4 + 2];
    float at3 = nattr[(size_t)n * 4 + 3];
    const float* r = nrow[g];
    float scs = 0.f, scv0 = 0.f, scv1 = 0.f, scv2 = 0.f;
#pragma unroll 4
    for (int u = 0; u < 32; ++u) {
        const float* ps = Wsc_s + (size_t)(u * 4) * 32 + w;
        const float* pv = Wsc_v + (size_t)(u * 4) * 32 + w;
        float cs = at0 * ps[0] + at1 * ps[32] + at2 * ps[64] + at3 * ps[96];
        float cv = at0 * pv[0] + at1 * pv[32] + at2 * pv[64] + at3 * pv[96];
        scs  += r[u] * cs;
        scv0 += r[32 + u * 3 + 0] * cv;
        scv1 += r[32 + u * 3 + 1] * cv;
        scv2 += r[32 + u * 3 + 2] * cv;
    }
    float* orow = out + (size_t)n * 128;
    orow[w] = sa + scs * sc_norm;
    orow[32 + w * 3 + 0] = va0 + scv0 * sc_norm;
    orow[32 + w * 3 + 1] = va1 + scv1 * sc_norm;
    orow[32 + w * 3 + 2] = va2 + scv2 * sc_norm;
}

extern "C" void kernel_launch(void* const* d_in, const int* in_sizes, int n_in,
                              void* d_out, int out_size, void* d_ws, size_t ws_size,
                              hipStream_t stream) {
    const float* nf    = (const float*)d_in[0];
    const float* nattr = (const float*)d_in[1];
    const float* ea    = (const float*)d_in[2];
    const float* ee    = (const float*)d_in[3];
    const float* W1_s  = (const float*)d_in[4];
    const float* W1_v  = (const float*)d_in[5];
    const float* fc1   = (const float*)d_in[6];
    const float* fc2   = (const float*)d_in[7];
    const float* W2_s  = (const float*)d_in[8];
    const float* W2_v  = (const float*)d_in[9];
    const float* Wsc_s = (const float*)d_in[10];
    const float* Wsc_v = (const float*)d_in[11];
    const int*   eidx  = (const int*)d_in[12];

    int N = in_sizes[0] / 128;
    int E = in_sizes[12] / 2;

    float* ws = (float*)d_ws;
    float* s1 = ws;                           // N*32
    float* v1 = s1 + (size_t)N * 32;          // N*96
    float* S  = v1 + (size_t)N * 96;          // N*64
    float* V  = S  + (size_t)N * 64;          // N*192
    int* cnt  = (int*)(V + (size_t)N * 192);  // N
    int* rs   = cnt + N;                      // N
    int* bsum = rs + N;                       // 64
    int* boff = bsum + 64;                    // 64
    int* perm = boff + 64;                    // E

    size_t needed = ((size_t)N * 384 + 2 * (size_t)N + 128 + (size_t)E) * 4;

    int nb_node = (N + 7) / 8;
    int nbE = (E + 255) / 256;

    if (ws_size >= needed) {
        hipMemsetAsync(cnt, 0, (size_t)N * sizeof(int), stream);
        node_prep<<<nb_node, 256, 0, stream>>>(nf, W1_s, W1_v, s1, v1, N);
        hist_kernel<<<nbE, 256, 0, stream>>>(eidx, cnt, E);
        int nbS = (N + 1023) / 1024;
        scan_a<<<nbS, 1024, 0, stream>>>(cnt, rs, bsum, N);
        scan_b<<<1, 64, 0, stream>>>(bsum, boff, nbS);
        scan_c<<<nbS, 1024, 0, stream>>>(rs, boff, N);
        scatter_kernel<<<nbE, 256, 0, stream>>>(eidx, rs, perm, E);
        reduce_kernel<<<nb_node, 256, 0, stream>>>(ea, ee, fc1, fc2, s1, v1, eidx,
                                                   perm, rs, cnt, S, V, N, E);
        node_final<<<nb_node, 256, 0, stream>>>(S, V, W2_s, W2_v, nf, nattr,
                                                Wsc_s, Wsc_v, (float*)d_out, N);
    } else {
        hipMemsetAsync(S, 0, (size_t)N * 256 * sizeof(float), stream);
        node_prep<<<nb_node, 256, 0, stream>>>(nf, W1_s, W1_v, s1, v1, N);
        long long tot = (long long)E * 32;
        int nb_edge = (int)((tot + 255) / 256);
        edge_kernel<<<nb_edge, 256, 0, stream>>>(ea, ee, fc1, fc2, s1, v1, eidx, S, V, E);
        node_final<<<nb_node, 256, 0, stream>>>(S, V, W2_s, W2_v, nf, nattr,
                                                Wsc_s, Wsc_v, (float*)d_out, N);
    }
}

// Round 4
// 295.972 us; speedup vs baseline: 2.8024x; 1.0278x over previous
//
#include <hip/hip_runtime.h>
#include <math.h>

// ---------------------------------------------------------------------------
// InteractionBlock: gather -> per-edge tensor-product -> scatter -> linear
// N=50000 nodes, E=800000 edges, MUL=32.
//
// Round-4:
//  * sv1 packed [n][u][4] = {s,vx,vy,vz}: phase-2 gather = 1 float4 load
//    (was 4 scalar-coalesced loads), +1-deep prefetch.
//  * rec k-major [g][13][32]: conflict-free LDS writes (was 16-way).
//  * SV packed [n][u][8]; reduce stores 2 float4s; node_final reads float4.
//  * node_final: W2+Wsc staged once per block as b128-packed LDS (60 KB),
//    4 nodes per 32-lane group (weight reads amortized 4x, VMEM -> LDS).
//  * hist folded into node_prep; fc1 staged in LDS in reduce.
//
// ws layout (4B units):
//   sv1[N*128] | SV[N*256] | cnt[N] | rs[N] | bsum[64] | boff[64] | perm[E]
// ---------------------------------------------------------------------------

__global__ __launch_bounds__(256) void node_prep(
    const float* __restrict__ nf, const float* __restrict__ W1_s,
    const float* __restrict__ W1_v, const int* __restrict__ eidx,
    int* __restrict__ cnt, float* __restrict__ sv1, int N, int E)
{
    __shared__ float w1s[1024];
    __shared__ float w1v[1024];
    __shared__ float nrow[8][128];

    // folded histogram of dst (grid covers E with stride loop)
    for (long long e = (long long)blockIdx.x * 256 + threadIdx.x; e < E;
         e += (long long)gridDim.x * 256)
        atomicAdd(cnt + eidx[(int)e], 1);

    int g = threadIdx.x >> 5;
    int w = threadIdx.x & 31;
    int n = blockIdx.x * 8 + g;

    for (int i = threadIdx.x; i < 1024; i += 256) {
        w1s[i] = W1_s[i];
        w1v[i] = W1_v[i];
    }
    if (n < N) {
        float4 q = *(const float4*)(nf + (size_t)n * 128 + w * 4);
        *(float4*)&nrow[g][w * 4] = q;
    }
    __syncthreads();
    if (n >= N) return;

    const float l1 = 0.17677669529663687f; // 1/sqrt(32)
    const float* r = nrow[g];
    float ss = 0.f, vx = 0.f, vy = 0.f, vz = 0.f;
#pragma unroll 8
    for (int u = 0; u < 32; ++u) {
        float ws = w1s[u * 32 + w];
        float wv = w1v[u * 32 + w];
        ss += r[u] * ws;
        vx += r[32 + u * 3 + 0] * wv;
        vy += r[32 + u * 3 + 1] * wv;
        vz += r[32 + u * 3 + 2] * wv;
    }
    *(float4*)(sv1 + (size_t)n * 128 + w * 4) =
        make_float4(ss * l1, vx * l1, vy * l1, vz * l1);
}

// ---------------- CSR build ----------------

__global__ __launch_bounds__(1024) void scan_a(
    const int* __restrict__ cnt, int* __restrict__ rs,
    int* __restrict__ bsum, int N)
{
    int i = blockIdx.x * 1024 + threadIdx.x;
    int lane = threadIdx.x & 63;
    int wid = threadIdx.x >> 6;
    int v = (i < N) ? cnt[i] : 0;
    int incl = v;
#pragma unroll
    for (int d = 1; d < 64; d <<= 1) {
        int t = __shfl_up(incl, d);
        if (lane >= d) incl += t;
    }
    __shared__ int wtot[16];
    __shared__ int woff[16];
    if (lane == 63) wtot[wid] = incl;
    __syncthreads();
    if (wid == 0) {
        int t = (lane < 16) ? wtot[lane] : 0;
        int s = t;
#pragma unroll
        for (int d = 1; d < 16; d <<= 1) {
            int q = __shfl_up(s, d);
            if (lane >= d) s += q;
        }
        if (lane < 16) woff[lane] = s - t;
        if (lane == 15) bsum[blockIdx.x] = s;
    }
    __syncthreads();
    if (i < N) rs[i] = woff[wid] + incl - v;
}

__global__ __launch_bounds__(64) void scan_b(
    const int* __restrict__ bsum, int* __restrict__ boff, int nb)
{
    int lane = threadIdx.x;
    int carry = 0;
    for (int base = 0; base < nb; base += 64) {
        int i = base + lane;
        int v = (i < nb) ? bsum[i] : 0;
        int s = v;
#pragma unroll
        for (int d = 1; d < 64; d <<= 1) {
            int t = __shfl_up(s, d);
            if (lane >= d) s += t;
        }
        if (i < nb) boff[i] = carry + s - v;
        carry += __shfl(s, 63);
    }
}

__global__ __launch_bounds__(1024) void scan_c(
    int* __restrict__ rs, const int* __restrict__ boff, int N)
{
    int i = blockIdx.x * 1024 + threadIdx.x;
    if (i < N) rs[i] += boff[blockIdx.x];
}

__global__ __launch_bounds__(256) void scatter_kernel(
    const int* __restrict__ eidx, int* __restrict__ rs,
    int* __restrict__ perm, int E)
{
    int e = blockIdx.x * 256 + threadIdx.x;
    if (e < E) {
        int d = eidx[e];
        int p = atomicAdd(rs + d, 1);
        perm[p] = e;
    }
}

// ---------------- per-node reduction (no atomics) ----------------

__global__ __launch_bounds__(256) void reduce_kernel(
    const float* __restrict__ ea, const float* __restrict__ ee,
    const float* __restrict__ fc1, const float* __restrict__ fc2,
    const float* __restrict__ sv1, const int* __restrict__ eidx,
    const int* __restrict__ perm, const int* __restrict__ rs_end,
    const int* __restrict__ cnt, float* __restrict__ SV, int N, int E)
{
    __shared__ float rec[8][13][32]; // k-major: conflict-free writes, bcast reads
    __shared__ float fc1s[64];
    int g = threadIdx.x >> 5;
    int u = threadIdx.x & 31;
    int n = blockIdx.x * 8 + g;

    if (threadIdx.x < 64) fc1s[threadIdx.x] = fc1[threadIdx.x];
    __syncthreads();
    if (n >= N) return;

    const float rs8 = 0.35355339059327373f;      // 1/sqrt(8)
    const float inv_sqrt3 = 0.5773502691896258f;

    float f2r[8][4];
#pragma unroll
    for (int k = 0; k < 8; ++k)
#pragma unroll
        for (int j = 0; j < 4; ++j)
            f2r[k][j] = fc2[k * 128 + j * 32 + u];

    int count = cnt[n];
    int end = rs_end[n];     // after scatter: rs[n] = start + cnt[n]
    int start = end - count;

    float aS0 = 0.f, aS1 = 0.f;
    float aV0x = 0.f, aV0y = 0.f, aV0z = 0.f;
    float aV1x = 0.f, aV1y = 0.f, aV1z = 0.f;

    for (int j0 = 0; j0 < count; j0 += 32) {
        int nk = count - j0; if (nk > 32) nk = 32;
        // phase 1: lane u computes MLP for edge slot u
        if (u < nk) {
            int e = perm[start + j0 + u];
            const float* eep = ee + (size_t)e * 8;
            float4 e0 = *(const float4*)eep;
            float4 e1 = *(const float4*)(eep + 4);
            float ev[8] = {e0.x, e0.y, e0.z, e0.w, e1.x, e1.y, e1.z, e1.w};
#pragma unroll
            for (int k = 0; k < 8; ++k) {
                float t = 0.f;
#pragma unroll
                for (int i = 0; i < 8; ++i) t += ev[i] * fc1s[i * 8 + k];
                t *= rs8;
                rec[g][k][u] = (t / (1.f + expf(-t))) * rs8;
            }
            float4 a4 = *(const float4*)(ea + (size_t)e * 4);
            rec[g][8][u]  = a4.x;
            rec[g][9][u]  = a4.y;
            rec[g][10][u] = a4.z;
            rec[g][11][u] = a4.w;
            rec[g][12][u] = __int_as_float(eidx[E + e]);
        }
        // phase 2 (same-wave LDS visibility; 1-deep prefetch of sv row)
        int s0 = __float_as_int(rec[g][12][0]);
        float4 svc = *(const float4*)(sv1 + (size_t)s0 * 128 + u * 4);
        for (int jj = 0; jj < nk; ++jj) {
            float4 svn = svc;
            if (jj + 1 < nk) {
                int s2 = __float_as_int(rec[g][12][jj + 1]);
                svn = *(const float4*)(sv1 + (size_t)s2 * 128 + u * 4);
            }
            float h0 = rec[g][0][jj], h1 = rec[g][1][jj];
            float h2 = rec[g][2][jj], h3 = rec[g][3][jj];
            float h4 = rec[g][4][jj], h5 = rec[g][5][jj];
            float h6 = rec[g][6][jj], h7 = rec[g][7][jj];
            float b0 = rec[g][8][jj], bx = rec[g][9][jj];
            float by = rec[g][10][jj], bz = rec[g][11][jj];

            float w0 = h0*f2r[0][0] + h1*f2r[1][0] + h2*f2r[2][0] + h3*f2r[3][0]
                     + h4*f2r[4][0] + h5*f2r[5][0] + h6*f2r[6][0] + h7*f2r[7][0];
            float w1 = h0*f2r[0][1] + h1*f2r[1][1] + h2*f2r[2][1] + h3*f2r[3][1]
                     + h4*f2r[4][1] + h5*f2r[5][1] + h6*f2r[6][1] + h7*f2r[7][1];
            float w2 = h0*f2r[0][2] + h1*f2r[1][2] + h2*f2r[2][2] + h3*f2r[3][2]
                     + h4*f2r[4][2] + h5*f2r[5][2] + h6*f2r[6][2] + h7*f2r[7][2];
            float w3 = h0*f2r[0][3] + h1*f2r[1][3] + h2*f2r[2][3] + h3*f2r[3][3]
                     + h4*f2r[4][3] + h5*f2r[5][3] + h6*f2r[6][3] + h7*f2r[7][3];

            float dv = svc.y * bx + svc.z * by + svc.w * bz;
            aS0 += w0 * svc.x * b0;
            aS1 += w3 * dv;
            float c1 = w1 * svc.x;
            aV0x += c1 * bx; aV0y += c1 * by; aV0z += c1 * bz;
            float c2 = w2 * b0;
            aV1x += c2 * svc.y; aV1y += c2 * svc.z; aV1z += c2 * svc.w;
            svc = svn;
        }
    }

    // packed SV[n][u][8] = {S0, S1*inv_sqrt3, V0x,V0y,V0z, V1x,V1y,V1z}
    float* o = SV + (size_t)n * 256 + u * 8;
    *(float4*)o       = make_float4(aS0, aS1 * inv_sqrt3, aV0x, aV0y);
    *(float4*)(o + 4) = make_float4(aV0z, aV1x, aV1y, aV1z);
}

// ---------------- fallback (atomic path, packed layouts) ----------------

__global__ __launch_bounds__(256) void edge_kernel(
    const float* __restrict__ ea, const float* __restrict__ ee,
    const float* __restrict__ fc1, const float* __restrict__ fc2,
    const float* __restrict__ sv1, const int* __restrict__ eidx,
    float* __restrict__ SV, int E)
{
    long long tid = (long long)blockIdx.x * 256 + threadIdx.x;
    int e = (int)(tid >> 5);
    int u = (int)(tid & 31);
    if (e >= E) return;
    const float rs8 = 0.35355339059327373f;
    const float inv_sqrt3 = 0.5773502691896258f;
    float ev[8];
#pragma unroll
    for (int i = 0; i < 8; ++i) ev[i] = ee[(size_t)e * 8 + i];
    float h[8];
#pragma unroll
    for (int k = 0; k < 8; ++k) {
        float t = 0.f;
#pragma unroll
        for (int i = 0; i < 8; ++i) t += ev[i] * fc1[i * 8 + k];
        t *= rs8;
        h[k] = t / (1.f + expf(-t));
    }
    float w0 = 0.f, w1 = 0.f, w2 = 0.f, w3 = 0.f;
#pragma unroll
    for (int k = 0; k < 8; ++k) {
        const float* f2 = fc2 + k * 128;
        float hk = h[k];
        w0 += hk * f2[u];
        w1 += hk * f2[32 + u];
        w2 += hk * f2[64 + u];
        w3 += hk * f2[96 + u];
    }
    w0 *= rs8; w1 *= rs8; w2 *= rs8; w3 *= rs8;
    int dst = eidx[e];
    int src = eidx[E + e];
    float a0 = ea[(size_t)e * 4 + 0];
    float ax = ea[(size_t)e * 4 + 1];
    float ay = ea[(size_t)e * 4 + 2];
    float az = ea[(size_t)e * 4 + 3];
    float4 sv = *(const float4*)(sv1 + (size_t)src * 128 + u * 4);
    float dv = sv.y * ax + sv.z * ay + sv.w * az;
    float* o = SV + (size_t)dst * 256 + u * 8;
    atomicAdd(o + 0, w0 * sv.x * a0);
    atomicAdd(o + 1, w3 * dv * inv_sqrt3);
    float c1 = w1 * sv.x;
    atomicAdd(o + 2, c1 * ax);
    atomicAdd(o + 3, c1 * ay);
    atomicAdd(o + 4, c1 * az);
    float c2 = w2 * a0;
    atomicAdd(o + 5, c2 * sv.y);
    atomicAdd(o + 6, c2 * sv.z);
    atomicAdd(o + 7, c2 * sv.w);
}

// ---------------- final linear + skip (block-staged packed weights) -------

__global__ __launch_bounds__(256) void node_final(
    const float* __restrict__ SV, const float* __restrict__ W2_s,
    const float* __restrict__ W2_v, const float* __restrict__ nf,
    const float* __restrict__ nattr, const float* __restrict__ Wsc_s,
    const float* __restrict__ Wsc_v, float* __restrict__ out, int N)
{
    __shared__ float wq[4096];   // 16 KB {w2s[u][w], w2s[u+32][w], w2v[u][w], w2v[u+32][w]}
    __shared__ float wsp[4096];  // 16 KB {Wsc_s[u][a][w]}a=0..3
    __shared__ float wvp[4096];  // 16 KB
    __shared__ float svt[8][8][32]; // 8 KB
    __shared__ float nrow[8][128];  // 4 KB

    int g = threadIdx.x >> 5;
    int w = threadIdx.x & 31;

    for (int i = threadIdx.x; i < 1024; i += 256) {  // i = u*32+w
        int uu = i >> 5, ww = i & 31;
        *(float4*)&wq[i * 4] = make_float4(W2_s[i], W2_s[i + 1024],
                                           W2_v[i], W2_v[i + 1024]);
        const float* ps = Wsc_s + (size_t)uu * 128 + ww;
        const float* pv = Wsc_v + (size_t)uu * 128 + ww;
        *(float4*)&wsp[i * 4] = make_float4(ps[0], ps[32], ps[64], ps[96]);
        *(float4*)&wvp[i * 4] = make_float4(pv[0], pv[32], pv[64], pv[96]);
    }
    __syncthreads();

    const float l2 = 0.125f;                    // 1/sqrt(64)
    const float sc_norm = 0.08838834764831843f; // 1/sqrt(128)

    for (int t = 0; t < 4; ++t) {
        int n = blockIdx.x * 32 + g * 4 + t;
        if (n >= N) continue;
        // stage this node's SV row (transposed) + nf row — same-wave, no barrier
        const float* svp = SV + (size_t)n * 256 + w * 8;
        float4 p0 = *(const float4*)svp;
        float4 p1 = *(const float4*)(svp + 4);
        svt[g][0][w] = p0.x; svt[g][1][w] = p0.y;
        svt[g][2][w] = p0.z; svt[g][3][w] = p0.w;
        svt[g][4][w] = p1.x; svt[g][5][w] = p1.y;
        svt[g][6][w] = p1.z; svt[g][7][w] = p1.w;
        float4 q = *(const float4*)(nf + (size_t)n * 128 + w * 4);
        *(float4*)&nrow[g][w * 4] = q;
        float at0 = nattr[(size_t)n * 4 + 0];
        float at1 = nattr[(size_t)n * 4 + 1];
        float at2 = nattr[(size_t)n * 4 + 2];
        float at3 = nattr[(size_t)n * 4 + 3];

        float sa = 0.f, va0 = 0.f, va1 = 0.f, va2 = 0.f;
        float scs = 0.f, scv0 = 0.f, scv1 = 0.f, scv2 = 0.f;
#pragma unroll
        for (int u = 0; u < 32; ++u) {
            float4 qw = *(const float4*)&wq[(u * 32 + w) * 4];
            sa  += svt[g][0][u] * qw.x + svt[g][1][u] * qw.y;
            va0 += svt[g][2][u] * qw.z + svt[g][5][u] * qw.w;
            va1 += svt[g][3][u] * qw.z + svt[g][6][u] * qw.w;
            va2 += svt[g][4][u] * qw.z + svt[g][7][u] * qw.w;
            float4 ps = *(const float4*)&wsp[(u * 32 + w) * 4];
            float4 pv = *(const float4*)&wvp[(u * 32 + w) * 4];
            float cs = at0 * ps.x + at1 * ps.y + at2 * ps.z + at3 * ps.w;
            float cv = at0 * pv.x + at1 * pv.y + at2 * pv.z + at3 * pv.w;
            scs  += nrow[g][u] * cs;
            scv0 += nrow[g][32 + u * 3 + 0] * cv;
            scv1 += nrow[g][32 + u * 3 + 1] * cv;
            scv2 += nrow[g][32 + u * 3 + 2] * cv;
        }
        float* orow = out + (size_t)n * 128;
        orow[w] = sa * l2 + scs * sc_norm;
        orow[32 + w * 3 + 0] = va0 * l2 + scv0 * sc_norm;
        orow[32 + w * 3 + 1] = va1 * l2 + scv1 * sc_norm;
        orow[32 + w * 3 + 2] = va2 * l2 + scv2 * sc_norm;
    }
}

extern "C" void kernel_launch(void* const* d_in, const int* in_sizes, int n_in,
                              void* d_out, int out_size, void* d_ws, size_t ws_size,
                              hipStream_t stream) {
    const float* nf    = (const float*)d_in[0];
    const float* nattr = (const float*)d_in[1];
    const float* ea    = (const float*)d_in[2];
    const float* ee    = (const float*)d_in[3];
    const float* W1_s  = (const float*)d_in[4];
    const float* W1_v  = (const float*)d_in[5];
    const float* fc1   = (const float*)d_in[6];
    const float* fc2   = (const float*)d_in[7];
    const float* W2_s  = (const float*)d_in[8];
    const float* W2_v  = (const float*)d_in[9];
    const float* Wsc_s = (const float*)d_in[10];
    const float* Wsc_v = (const float*)d_in[11];
    const int*   eidx  = (const int*)d_in[12];

    int N = in_sizes[0] / 128;
    int E = in_sizes[12] / 2;

    float* ws = (float*)d_ws;
    float* sv1 = ws;                            // N*128
    float* SV  = sv1 + (size_t)N * 128;         // N*256
    int* cnt  = (int*)(SV + (size_t)N * 256);   // N
    int* rs   = cnt + N;                        // N
    int* bsum = rs + N;                         // 64
    int* boff = bsum + 64;                      // 64
    int* perm = boff + 64;                      // E

    size_t needed = ((size_t)N * 384 + 2 * (size_t)N + 128 + (size_t)E) * 4;

    int nb_node = (N + 7) / 8;
    int nbE = (E + 255) / 256;
    int nb_final = (N + 31) / 32;

    if (ws_size >= needed) {
        hipMemsetAsync(cnt, 0, (size_t)N * sizeof(int), stream);
        node_prep<<<nb_node, 256, 0, stream>>>(nf, W1_s, W1_v, eidx, cnt, sv1, N, E);
        int nbS = (N + 1023) / 1024;
        scan_a<<<nbS, 1024, 0, stream>>>(cnt, rs, bsum, N);
        scan_b<<<1, 64, 0, stream>>>(bsum, boff, nbS);
        scan_c<<<nbS, 1024, 0, stream>>>(rs, boff, N);
        scatter_kernel<<<nbE, 256, 0, stream>>>(eidx, rs, perm, E);
        reduce_kernel<<<nb_node, 256, 0, stream>>>(ea, ee, fc1, fc2, sv1, eidx,
                                                   perm, rs, cnt, SV, N, E);
        node_final<<<nb_final, 256, 0, stream>>>(SV, W2_s, W2_v, nf, nattr,
                                                 Wsc_s, Wsc_v, (float*)d_out, N);
    } else {
        hipMemsetAsync(SV, 0, (size_t)N * 256 * sizeof(float), stream);
        node_prep<<<nb_node, 256, 0, stream>>>(nf, W1_s, W1_v, eidx, cnt, sv1, N, E);
        long long tot = (long long)E * 32;
        int nb_edge = (int)((tot + 255) / 256);
        edge_kernel<<<nb_edge, 256, 0, stream>>>(ea, ee, fc1, fc2, sv1, eidx, SV, E);
        node_final<<<nb_final, 256, 0, stream>>>(SV, W2_s, W2_v, nf, nattr,
                                                 Wsc_s, Wsc_v, (float*)d_out, N);
    }
}